// Round 5
// baseline (2603.340 us; speedup 1.0000x reference)
//
#include <hip/hip_runtime.h>

#define NPTS    1024
#define DIM     16
#define GRAPHS  64
#define NITERS  20
#define THREADS 1024
#define NWAVES  (THREADS / 64)
#define RT      4        // 16-row tiles per wave (16 waves x 64 rows)
#define NCHUNK  16       // 64 j-tiles, 4 per chunk

typedef __bf16 bf16x8 __attribute__((ext_vector_type(8)));
typedef __bf16 bf16x4 __attribute__((ext_vector_type(4)));
typedef float  f32x4  __attribute__((ext_vector_type(4)));

#define KLOG 577.07801635558536f      // log2(e)/eps, eps = 0.05^2
#define CLSE 0.0017328679513998633f   // eps*ln2   (KLOG*CLSE == 1)

static __device__ __forceinline__ float fexp2(float x){ return __builtin_amdgcn_exp2f(x); }
static __device__ __forceinline__ float flog2(float x){ return __builtin_amdgcn_logf(x); }

static __device__ __forceinline__ float halfsq16(const float* p)
{
    const float4* v = (const float4*)p;
    float a = 0.0f;
    #pragma unroll
    for (int c = 0; c < 4; ++c) {
        const float4 q = v[c];
        a = fmaf(q.x, q.x, a); a = fmaf(q.y, q.y, a);
        a = fmaf(q.z, q.z, a); a = fmaf(q.w, q.w, a);
    }
    return 0.5f * a;
}

// global f32 cloud -> LDS split-bf16 (hi, lo), optionally pre-scaled
static __device__ __forceinline__ void split_store(
    __bf16* __restrict__ dh, __bf16* __restrict__ dl,
    const float* __restrict__ src, const float scale, const int tid)
{
    const float4* s4 = (const float4*)src;
    #pragma unroll 1
    for (int k = 0; k < (NPTS * DIM / 4) / THREADS; ++k) {
        const int idx = tid + k * THREADS;
        const float4 v = s4[idx];
        const float f0 = v.x * scale, f1 = v.y * scale,
                    f2 = v.z * scale, f3 = v.w * scale;
        bf16x4 h, l;
        h[0] = (__bf16)f0; l[0] = (__bf16)(f0 - (float)h[0]);
        h[1] = (__bf16)f1; l[1] = (__bf16)(f1 - (float)h[1]);
        h[2] = (__bf16)f2; l[2] = (__bf16)(f2 - (float)h[2]);
        h[3] = (__bf16)f3; l[3] = (__bf16)(f3 - (float)h[3]);
        *(bf16x4*)(dh + idx * 4) = h;
        *(bf16x4*)(dl + idx * 4) = l;
    }
}

// One half-iteration: per wave, online-LSE over all 1024 cols for its 64
// rows; returns sum of row-LSEs (x16 column-lane duplication) and writes
// new messages  -10 - lse  into sB.
static __device__ __forceinline__ float sink_pass(
    const __bf16* __restrict__ rH, const __bf16* __restrict__ rL,
    const __bf16* __restrict__ cH, const __bf16* __restrict__ cL,
    float* __restrict__ sB, const int wbase, const int lane)
{
    const int g  = lane >> 4;
    const int n  = lane & 15;
    const int gh = g & 1;

    // A fragments: [row-hi | row-lo] along K=32 (rows pre-scaled by KLOG)
    bf16x8 A[RT];
    {
        const __bf16* ap = (g < 2 ? rH : rL) + (wbase + n) * DIM + gh * 8;
        #pragma unroll
        for (int rt = 0; rt < RT; ++rt)
            A[rt] = *(const bf16x8*)(ap + rt * (16 * DIM));
    }

    float m[RT][4], s[RT][4];
    #pragma unroll
    for (int rt = 0; rt < RT; ++rt) {
        #pragma unroll
        for (int e = 0; e < 4; ++e) { m[rt][e] = -3.0e38f; s[rt][e] = 0.0f; }
    }

    const __bf16* b1p = cH + n * DIM + gh * 8;   // B1 = [yh | yh]
    const __bf16* b2p = cL + n * DIM + gh * 8;   // B2 = [yl | yl]
    const float*  tp  = sB + n;

    #pragma unroll 1
    for (int c = 0; c < NCHUNK; ++c) {
        bf16x8 B1[4], B2[4];
        float  t[4];
        const int off = c * (4 * 16 * DIM);
        #pragma unroll
        for (int q = 0; q < 4; ++q) {
            B1[q] = *(const bf16x8*)(b1p + off + q * (16 * DIM));
            B2[q] = *(const bf16x8*)(b2p + off + q * (16 * DIM));
            t[q]  = tp[c * 64 + q * 16];
        }
        #pragma unroll
        for (int rt = 0; rt < RT; ++rt) {
            f32x4 w[4];
            #pragma unroll
            for (int q = 0; q < 4; ++q) {
                f32x4 acc = { t[q], t[q], t[q], t[q] };   // t_j injected as C-init
                acc = __builtin_amdgcn_mfma_f32_16x16x32_bf16(A[rt], B2[q], acc, 0, 0, 0);
                acc = __builtin_amdgcn_mfma_f32_16x16x32_bf16(A[rt], B1[q], acc, 0, 0, 0);
                w[q] = acc;
            }
            #pragma unroll
            for (int e = 0; e < 4; ++e) {
                const float mc = fmaxf(fmaxf(w[0][e], w[1][e]),
                                       fmaxf(w[2][e], w[3][e]));
                const float mn = fmaxf(m[rt][e], mc);
                const float es = (fexp2(w[0][e] - mn) + fexp2(w[1][e] - mn))
                               + (fexp2(w[2][e] - mn) + fexp2(w[3][e] - mn));
                s[rt][e] = fmaf(s[rt][e], fexp2(m[rt][e] - mn), es);
                m[rt][e] = mn;
            }
        }
    }

    __syncthreads();     // all reads of sB complete block-wide

    // merge (m,s) across the 16 column-class lanes, write new messages
    float lsum = 0.0f;
    #pragma unroll
    for (int rt = 0; rt < RT; ++rt) {
        float msg[4];
        #pragma unroll
        for (int e = 0; e < 4; ++e) {
            float mm = m[rt][e], ss = s[rt][e];
            #pragma unroll
            for (int d = 1; d < 16; d <<= 1) {
                const float mo = __shfl_xor(mm, d, 64);
                const float so = __shfl_xor(ss, d, 64);
                const float mn = fmaxf(mm, mo);
                ss = fmaf(ss, fexp2(mm - mn), so * fexp2(mo - mn));
                mm = mn;
            }
            const float l = mm + flog2(ss);
            lsum += l;
            msg[e] = -10.0f - l;
        }
        if (n == 0) {     // rows g*4..g*4+3 of this row-tile
            f32x4 v = { msg[0], msg[1], msg[2], msg[3] };
            *(f32x4*)(sB + wbase + rt * 16 + g * 4) = v;
        }
    }
    __syncthreads();
    return lsum;
}

__global__ __launch_bounds__(THREADS)
void sinkhorn_kernel(const float* __restrict__ xg,
                     const float* __restrict__ yg,
                     float* __restrict__ out)
{
    extern __shared__ char ldsraw[];
    __bf16* sxh = (__bf16*)ldsraw;              // [1024][16] hi of K*x
    __bf16* sxl = sxh + NPTS * DIM;             // lo of K*x
    __bf16* syh = sxl + NPTS * DIM;             // hi of y
    __bf16* syl = syh + NPTS * DIM;             // lo of y
    float*  sB  = (float*)(syl + NPTS * DIM);   // [1024] messages (log2 units)

    const int tid   = threadIdx.x;
    const int lane  = tid & 63;
    const int wave  = tid >> 6;
    const int wbase = wave * (RT * 16);

    const int graph = blockIdx.x / 3;
    const int term  = blockIdx.x - graph * 3;   // 0:(x,y) 1:(x,x) 2:(y,y)
    const float* xb = xg + (size_t)graph * (NPTS * DIM);
    const float* yb = yg + (size_t)graph * (NPTS * DIM);
    const float* Xp = (term == 2) ? yb : xb;
    const float* Yp = (term == 1) ? xb : yb;

    split_store(sxh, sxl, Xp, KLOG, tid);       // row side carries the 1/eps scale
    split_store(syh, syl, Yp, 1.0f, tid);

    // quadratic terms (exact f32) + message init (thread = row)
    float csum;
    {
        const float hx = halfsq16(Xp + tid * DIM);
        const float hy = halfsq16(Yp + tid * DIM);
        csum = hx + hy;
        sB[tid] = fmaf(-KLOG, hy, -10.0f);      // t_j for g = 0
    }
    __syncthreads();

    float fsum = 0.0f, gsum = 0.0f;
    #pragma unroll 1
    for (int it = 0; it < NITERS; ++it) {
        fsum = sink_pass(sxh, sxl, syh, syl, sB, wbase, lane);   // f-update
        gsum = sink_pass(syh, syl, sxh, sxl, sB, wbase, lane);   // g-update
    }
    fsum = sink_pass(sxh, sxl, syh, syl, sB, wbase, lane);       // final f

    // OT = [csum - CLSE*(sum lse_f + sum lse_g)] / NPTS  (lse sums x16 dup)
    float v = fmaf(-CLSE, (fsum + gsum) * (1.0f / 16.0f), csum);
    #pragma unroll
    for (int off = 32; off; off >>= 1) v += __shfl_down(v, off, 64);
    if (lane == 0) sB[wave] = v;
    __syncthreads();
    if (tid == 0) {
        float tot = 0.0f;
        #pragma unroll
        for (int w = 0; w < NWAVES; ++w) tot += sB[w];
        const float wgt = ((term == 0) ? 1.0f : -0.5f)
                          / ((float)GRAPHS * (float)NPTS);
        atomicAdd(out, wgt * tot);
    }
}

extern "C" void kernel_launch(void* const* d_in, const int* in_sizes, int n_in,
                              void* d_out, int out_size, void* d_ws, size_t ws_size,
                              hipStream_t stream)
{
    (void)in_sizes; (void)n_in; (void)d_ws; (void)ws_size; (void)out_size;
    const float* x = (const float*)d_in[0];
    const float* y = (const float*)d_in[1];
    float* out = (float*)d_out;

    constexpr size_t LDSB = 4 * NPTS * DIM * sizeof(__bf16)
                          + NPTS * sizeof(float);          // 132 KiB
    hipFuncSetAttribute((const void*)sinkhorn_kernel,
                        hipFuncAttributeMaxDynamicSharedMemorySize, (int)LDSB);

    hipMemsetAsync(out, 0, sizeof(float), stream);
    hipLaunchKernelGGL(sinkhorn_kernel, dim3(GRAPHS * 3), dim3(THREADS), LDSB,
                       stream, x, y, out);
}

// Round 6
// 2594.478 us; speedup vs baseline: 1.0034x; 1.0034x over previous
//
#include <hip/hip_runtime.h>

#define NPTS    1024
#define DIM     16
#define GRAPHS  64
#define NITERS  20
#define THREADS 1024
#define NWAVES  (THREADS / 64)
#define RT      4        // 16-row tiles per wave (16 waves x 64 rows)
#define NCHUNK  16       // 64 j-tiles, 4 per chunk

typedef __bf16 bf16x8 __attribute__((ext_vector_type(8)));
typedef __bf16 bf16x4 __attribute__((ext_vector_type(4)));
typedef float  f32x4  __attribute__((ext_vector_type(4)));

#define KLOG 577.07801635558536f      // log2(e)/eps, eps = 0.05^2
#define CLSE 0.0017328679513998633f   // eps*ln2   (KLOG*CLSE == 1)

static __device__ __forceinline__ float fexp2(float x){ return __builtin_amdgcn_exp2f(x); }
static __device__ __forceinline__ float flog2(float x){ return __builtin_amdgcn_logf(x); }

static __device__ __forceinline__ float halfsq16(const float* p)
{
    const float4* v = (const float4*)p;
    float a = 0.0f;
    #pragma unroll
    for (int c = 0; c < 4; ++c) {
        const float4 q = v[c];
        a = fmaf(q.x, q.x, a); a = fmaf(q.y, q.y, a);
        a = fmaf(q.z, q.z, a); a = fmaf(q.w, q.w, a);
    }
    return 0.5f * a;
}

// global f32 cloud -> LDS split-bf16 (hi, lo), optionally pre-scaled
static __device__ __forceinline__ void split_store(
    __bf16* __restrict__ dh, __bf16* __restrict__ dl,
    const float* __restrict__ src, const float scale, const int tid)
{
    const float4* s4 = (const float4*)src;
    #pragma unroll 1
    for (int k = 0; k < (NPTS * DIM / 4) / THREADS; ++k) {
        const int idx = tid + k * THREADS;
        const float4 v = s4[idx];
        const float f0 = v.x * scale, f1 = v.y * scale,
                    f2 = v.z * scale, f3 = v.w * scale;
        bf16x4 h, l;
        h[0] = (__bf16)f0; l[0] = (__bf16)(f0 - (float)h[0]);
        h[1] = (__bf16)f1; l[1] = (__bf16)(f1 - (float)h[1]);
        h[2] = (__bf16)f2; l[2] = (__bf16)(f2 - (float)h[2]);
        h[3] = (__bf16)f3; l[3] = (__bf16)(f3 - (float)h[3]);
        *(bf16x4*)(dh + idx * 4) = h;
        *(bf16x4*)(dl + idx * 4) = l;
    }
}

// One half-iteration: per wave, online-LSE over all 1024 cols for its 64
// rows; returns sum of row-LSEs (x16 column-lane duplication) and writes
// new messages  -10 - lse  into sB.
static __device__ __forceinline__ float sink_pass(
    const __bf16* __restrict__ rH, const __bf16* __restrict__ rL,
    const __bf16* __restrict__ cH, const __bf16* __restrict__ cL,
    float* __restrict__ sB, const int wbase, const int lane)
{
    const int g  = lane >> 4;
    const int n  = lane & 15;
    const int gh = g & 1;

    // A fragments: [row-hi | row-lo] along K=32 (rows pre-scaled by KLOG)
    bf16x8 A[RT];
    {
        const __bf16* ap = (g < 2 ? rH : rL) + (wbase + n) * DIM + gh * 8;
        #pragma unroll
        for (int rt = 0; rt < RT; ++rt)
            A[rt] = *(const bf16x8*)(ap + rt * (16 * DIM));
    }

    float m[RT][4], s[RT][4];
    #pragma unroll
    for (int rt = 0; rt < RT; ++rt) {
        #pragma unroll
        for (int e = 0; e < 4; ++e) { m[rt][e] = -3.0e38f; s[rt][e] = 0.0f; }
    }

    const __bf16* b1p = cH + n * DIM + gh * 8;   // B1 = [yh | yh]
    const __bf16* b2p = cL + n * DIM + gh * 8;   // B2 = [yl | yl]
    const float*  tp  = sB + n;

    #pragma unroll 1
    for (int c = 0; c < NCHUNK; ++c) {
        bf16x8 B1[4], B2[4];
        float  t[4];
        const int off = c * (4 * 16 * DIM);
        #pragma unroll
        for (int q = 0; q < 4; ++q) {
            B1[q] = *(const bf16x8*)(b1p + off + q * (16 * DIM));
            B2[q] = *(const bf16x8*)(b2p + off + q * (16 * DIM));
            t[q]  = tp[c * 64 + q * 16];
        }
        #pragma unroll
        for (int rt = 0; rt < RT; ++rt) {
            f32x4 w[4];
            #pragma unroll
            for (int q = 0; q < 4; ++q) {
                f32x4 acc = { t[q], t[q], t[q], t[q] };   // t_j injected as C-init
                acc = __builtin_amdgcn_mfma_f32_16x16x32_bf16(A[rt], B2[q], acc, 0, 0, 0);
                acc = __builtin_amdgcn_mfma_f32_16x16x32_bf16(A[rt], B1[q], acc, 0, 0, 0);
                w[q] = acc;
            }
            #pragma unroll
            for (int e = 0; e < 4; ++e) {
                const float mc = fmaxf(fmaxf(w[0][e], w[1][e]),
                                       fmaxf(w[2][e], w[3][e]));
                const float mn = fmaxf(m[rt][e], mc);
                const float es = (fexp2(w[0][e] - mn) + fexp2(w[1][e] - mn))
                               + (fexp2(w[2][e] - mn) + fexp2(w[3][e] - mn));
                s[rt][e] = fmaf(s[rt][e], fexp2(m[rt][e] - mn), es);
                m[rt][e] = mn;
            }
        }
    }

    __syncthreads();     // all reads of sB complete block-wide

    // merge (m,s) across the 16 column-class lanes, write new messages
    float lsum = 0.0f;
    #pragma unroll
    for (int rt = 0; rt < RT; ++rt) {
        float msg[4];
        #pragma unroll
        for (int e = 0; e < 4; ++e) {
            float mm = m[rt][e], ss = s[rt][e];
            #pragma unroll
            for (int d = 1; d < 16; d <<= 1) {
                const float mo = __shfl_xor(mm, d, 64);
                const float so = __shfl_xor(ss, d, 64);
                const float mn = fmaxf(mm, mo);
                ss = fmaf(ss, fexp2(mm - mn), so * fexp2(mo - mn));
                mm = mn;
            }
            const float l = mm + flog2(ss);
            lsum += l;
            msg[e] = -10.0f - l;
        }
        if (n == 0) {     // rows g*4..g*4+3 of this row-tile
            f32x4 v = { msg[0], msg[1], msg[2], msg[3] };
            *(f32x4*)(sB + wbase + rt * 16 + g * 4) = v;
        }
    }
    __syncthreads();
    return lsum;
}

__global__ __launch_bounds__(THREADS)
__attribute__((amdgpu_waves_per_eu(4, 4)))      // LDS caps us at 4 waves/SIMD;
                                                 // stop occupancy-driven spilling
void sinkhorn_kernel(const float* __restrict__ xg,
                     const float* __restrict__ yg,
                     float* __restrict__ out)
{
    extern __shared__ char ldsraw[];
    __bf16* sxh = (__bf16*)ldsraw;              // [1024][16] hi of K*x
    __bf16* sxl = sxh + NPTS * DIM;             // lo of K*x
    __bf16* syh = sxl + NPTS * DIM;             // hi of y
    __bf16* syl = syh + NPTS * DIM;             // lo of y
    float*  sB  = (float*)(syl + NPTS * DIM);   // [1024] messages (log2 units)

    const int tid   = threadIdx.x;
    const int lane  = tid & 63;
    const int wave  = tid >> 6;
    const int wbase = wave * (RT * 16);

    const int graph = blockIdx.x / 3;
    const int term  = blockIdx.x - graph * 3;   // 0:(x,y) 1:(x,x) 2:(y,y)
    const float* xb = xg + (size_t)graph * (NPTS * DIM);
    const float* yb = yg + (size_t)graph * (NPTS * DIM);
    const float* Xp = (term == 2) ? yb : xb;
    const float* Yp = (term == 1) ? xb : yb;

    split_store(sxh, sxl, Xp, KLOG, tid);       // row side carries the 1/eps scale
    split_store(syh, syl, Yp, 1.0f, tid);

    // quadratic terms (exact f32) + message init (thread = row)
    float csum;
    {
        const float hx = halfsq16(Xp + tid * DIM);
        const float hy = halfsq16(Yp + tid * DIM);
        csum = hx + hy;
        sB[tid] = fmaf(-KLOG, hy, -10.0f);      // t_j for g = 0
    }
    __syncthreads();

    float fsum = 0.0f, gsum = 0.0f;
    #pragma unroll 1
    for (int it = 0; it < NITERS; ++it) {
        fsum = sink_pass(sxh, sxl, syh, syl, sB, wbase, lane);   // f-update
        gsum = sink_pass(syh, syl, sxh, sxl, sB, wbase, lane);   // g-update
    }
    fsum = sink_pass(sxh, sxl, syh, syl, sB, wbase, lane);       // final f

    // OT = [csum - CLSE*(sum lse_f + sum lse_g)] / NPTS  (lse sums x16 dup)
    float v = fmaf(-CLSE, (fsum + gsum) * (1.0f / 16.0f), csum);
    #pragma unroll
    for (int off = 32; off; off >>= 1) v += __shfl_down(v, off, 64);
    if (lane == 0) sB[wave] = v;
    __syncthreads();
    if (tid == 0) {
        float tot = 0.0f;
        #pragma unroll
        for (int w = 0; w < NWAVES; ++w) tot += sB[w];
        const float wgt = ((term == 0) ? 1.0f : -0.5f)
                          / ((float)GRAPHS * (float)NPTS);
        atomicAdd(out, wgt * tot);
    }
}

extern "C" void kernel_launch(void* const* d_in, const int* in_sizes, int n_in,
                              void* d_out, int out_size, void* d_ws, size_t ws_size,
                              hipStream_t stream)
{
    (void)in_sizes; (void)n_in; (void)d_ws; (void)ws_size; (void)out_size;
    const float* x = (const float*)d_in[0];
    const float* y = (const float*)d_in[1];
    float* out = (float*)d_out;

    constexpr size_t LDSB = 4 * NPTS * DIM * sizeof(__bf16)
                          + NPTS * sizeof(float);          // 132 KiB
    hipFuncSetAttribute((const void*)sinkhorn_kernel,
                        hipFuncAttributeMaxDynamicSharedMemorySize, (int)LDSB);

    hipMemsetAsync(out, 0, sizeof(float), stream);
    hipLaunchKernelGGL(sinkhorn_kernel, dim3(GRAPHS * 3), dim3(THREADS), LDSB,
                       stream, x, y, out);
}

// Round 7
// 1966.766 us; speedup vs baseline: 1.3237x; 1.3192x over previous
//
#include <hip/hip_runtime.h>

#define NPTS    1024
#define DIM     16
#define GRAPHS  64
#define NITERS  20
#define THREADS 1024
#define NWAVES  (THREADS / 64)
#define RT      4        // 16-row tiles per wave (16 waves x 64 rows)
#define NCHUNK  16       // 64 j-tiles, 4 per chunk
#define WIN     80.0f    // prune window (log2 units); covers est-err(<=37)+mass(25)

typedef __bf16 bf16x8 __attribute__((ext_vector_type(8)));
typedef __bf16 bf16x4 __attribute__((ext_vector_type(4)));
typedef float  f32x4  __attribute__((ext_vector_type(4)));

#define KLOG 577.07801635558536f      // log2(e)/eps, eps = 0.05^2
#define CLSE 0.0017328679513998633f   // eps*ln2   (KLOG*CLSE == 1)

static __device__ __forceinline__ float fexp2(float x){ return __builtin_amdgcn_exp2f(x); }
static __device__ __forceinline__ float flog2(float x){ return __builtin_amdgcn_logf(x); }

static __device__ __forceinline__ float halfsq16(const float* p)
{
    const float4* v = (const float4*)p;
    float a = 0.0f;
    #pragma unroll
    for (int c = 0; c < 4; ++c) {
        const float4 q = v[c];
        a = fmaf(q.x, q.x, a); a = fmaf(q.y, q.y, a);
        a = fmaf(q.z, q.z, a); a = fmaf(q.w, q.w, a);
    }
    return 0.5f * a;
}

// global f32 cloud -> LDS split-bf16 (hi, lo), optionally pre-scaled
static __device__ __forceinline__ void split_store(
    __bf16* __restrict__ dh, __bf16* __restrict__ dl,
    const float* __restrict__ src, const float scale, const int tid)
{
    const float4* s4 = (const float4*)src;
    #pragma unroll 1
    for (int k = 0; k < (NPTS * DIM / 4) / THREADS; ++k) {
        const int idx = tid + k * THREADS;
        const float4 v = s4[idx];
        const float f0 = v.x * scale, f1 = v.y * scale,
                    f2 = v.z * scale, f3 = v.w * scale;
        bf16x4 h, l;
        h[0] = (__bf16)f0; l[0] = (__bf16)(f0 - (float)h[0]);
        h[1] = (__bf16)f1; l[1] = (__bf16)(f1 - (float)h[1]);
        h[2] = (__bf16)f2; l[2] = (__bf16)(f2 - (float)h[2]);
        h[3] = (__bf16)f3; l[3] = (__bf16)(f3 - (float)h[3]);
        *(bf16x4*)(dh + idx * 4) = h;
        *(bf16x4*)(dl + idx * 4) = l;
    }
}

// One half-iteration, two-phase:
//  pass 1: m[row] = max_j (t_j + approx dot)  (B = hi only, no trans)
//  pass 2: s[row] = sum_j 2^{t_j + dot - m}, quadrant-pruned at -WIN
// Returns sum of row-LSEs (x16 column-lane duplication); writes -10-lse to sB.
static __device__ __forceinline__ float sink_pass(
    const __bf16* __restrict__ rH, const __bf16* __restrict__ rL,
    const __bf16* __restrict__ cH, const __bf16* __restrict__ cL,
    float* __restrict__ sB, const int wbase, const int lane)
{
    const int g  = lane >> 4;
    const int n  = lane & 15;
    const int gh = g & 1;

    // A fragments: [row-hi | row-lo] along K=32 (rows pre-scaled by KLOG)
    bf16x8 A[RT];
    {
        const __bf16* ap = (g < 2 ? rH : rL) + (wbase + n) * DIM + gh * 8;
        #pragma unroll
        for (int rt = 0; rt < RT; ++rt)
            A[rt] = *(const bf16x8*)(ap + rt * (16 * DIM));
    }

    const __bf16* b1p = cH + n * DIM + gh * 8;   // [yh | yh]
    const __bf16* b2p = cL + n * DIM + gh * 8;   // [yl | yl]
    const float*  tp  = sB + n;

    // ---------------- pass 1: row maxima (approx, trans-free) ----------------
    float m[RT][4];
    #pragma unroll
    for (int rt = 0; rt < RT; ++rt) {
        #pragma unroll
        for (int e = 0; e < 4; ++e) m[rt][e] = -3.0e38f;
    }

    #pragma unroll 1
    for (int c = 0; c < NCHUNK; ++c) {
        float t[4];
        #pragma unroll
        for (int q = 0; q < 4; ++q) t[q] = tp[c * 64 + q * 16];
        const int off = c * (4 * 16 * DIM);
        #pragma unroll
        for (int qq = 0; qq < 2; ++qq) {           // q-pairs: lower reg pressure
            bf16x8 B[2];
            B[0] = *(const bf16x8*)(b1p + off + (qq * 2 + 0) * (16 * DIM));
            B[1] = *(const bf16x8*)(b1p + off + (qq * 2 + 1) * (16 * DIM));
            #pragma unroll
            for (int rt = 0; rt < RT; ++rt) {
                #pragma unroll
                for (int p = 0; p < 2; ++p) {
                    const float tq = t[qq * 2 + p];
                    f32x4 acc = { tq, tq, tq, tq };
                    acc = __builtin_amdgcn_mfma_f32_16x16x32_bf16(A[rt], B[p], acc, 0, 0, 0);
                    #pragma unroll
                    for (int e = 0; e < 4; ++e)
                        m[rt][e] = fmaxf(m[rt][e], acc[e]);
                }
            }
        }
    }

    // merge maxima across the 16 column-class lanes
    #pragma unroll
    for (int rt = 0; rt < RT; ++rt) {
        #pragma unroll
        for (int e = 0; e < 4; ++e) {
            float mm = m[rt][e];
            #pragma unroll
            for (int d = 1; d < 16; d <<= 1)
                mm = fmaxf(mm, __shfl_xor(mm, d, 64));
            m[rt][e] = mm;
        }
    }

    // ---------------- pass 2: pruned exp-sums (shared m) ----------------
    float s[RT][4];
    #pragma unroll
    for (int rt = 0; rt < RT; ++rt) {
        #pragma unroll
        for (int e = 0; e < 4; ++e) s[rt][e] = 0.0f;
    }

    #pragma unroll 1
    for (int c = 0; c < NCHUNK; ++c) {
        float t[4];
        #pragma unroll
        for (int q = 0; q < 4; ++q) t[q] = tp[c * 64 + q * 16];
        const int off = c * (4 * 16 * DIM);
        #pragma unroll
        for (int qq = 0; qq < 2; ++qq) {
            bf16x8 B1[2], B2[2];
            B1[0] = *(const bf16x8*)(b1p + off + (qq * 2 + 0) * (16 * DIM));
            B1[1] = *(const bf16x8*)(b1p + off + (qq * 2 + 1) * (16 * DIM));
            B2[0] = *(const bf16x8*)(b2p + off + (qq * 2 + 0) * (16 * DIM));
            B2[1] = *(const bf16x8*)(b2p + off + (qq * 2 + 1) * (16 * DIM));
            #pragma unroll
            for (int rt = 0; rt < RT; ++rt) {
                #pragma unroll
                for (int p = 0; p < 2; ++p) {
                    const float tq = t[qq * 2 + p];
                    f32x4 acc = { tq - m[rt][0], tq - m[rt][1],
                                  tq - m[rt][2], tq - m[rt][3] };
                    acc = __builtin_amdgcn_mfma_f32_16x16x32_bf16(A[rt], B2[p], acc, 0, 0, 0);
                    acc = __builtin_amdgcn_mfma_f32_16x16x32_bf16(A[rt], B1[p], acc, 0, 0, 0);
                    const float h = fmaxf(fmaxf(acc[0], acc[1]),
                                          fmaxf(acc[2], acc[3]));
                    if (__any(h > -WIN)) {      // quadrant carries visible mass
                        s[rt][0] += fexp2(acc[0]);
                        s[rt][1] += fexp2(acc[1]);
                        s[rt][2] += fexp2(acc[2]);
                        s[rt][3] += fexp2(acc[3]);
                    }
                }
            }
        }
    }

    // merge sums across the 16 column-class lanes (m already shared)
    float lsum = 0.0f;
    float msg[RT][4];
    #pragma unroll
    for (int rt = 0; rt < RT; ++rt) {
        #pragma unroll
        for (int e = 0; e < 4; ++e) {
            float ss = s[rt][e];
            #pragma unroll
            for (int d = 1; d < 16; d <<= 1)
                ss += __shfl_xor(ss, d, 64);
            const float l = m[rt][e] + flog2(ss);
            lsum += l;
            msg[rt][e] = -10.0f - l;
        }
    }

    __syncthreads();     // all reads of sB complete block-wide
    if (n == 0) {
        #pragma unroll
        for (int rt = 0; rt < RT; ++rt) {
            f32x4 v = { msg[rt][0], msg[rt][1], msg[rt][2], msg[rt][3] };
            *(f32x4*)(sB + wbase + rt * 16 + g * 4) = v;
        }
    }
    __syncthreads();
    return lsum;
}

__global__ __launch_bounds__(THREADS)
void sinkhorn_kernel(const float* __restrict__ xg,
                     const float* __restrict__ yg,
                     float* __restrict__ out)
{
    extern __shared__ char ldsraw[];
    __bf16* sxh = (__bf16*)ldsraw;              // [1024][16] hi of K*x
    __bf16* sxl = sxh + NPTS * DIM;             // lo of K*x
    __bf16* syh = sxl + NPTS * DIM;             // hi of y
    __bf16* syl = syh + NPTS * DIM;             // lo of y
    float*  sB  = (float*)(syl + NPTS * DIM);   // [1024] messages (log2 units)

    const int tid   = threadIdx.x;
    const int lane  = tid & 63;
    const int wave  = tid >> 6;
    const int wbase = wave * (RT * 16);

    const int graph = blockIdx.x / 3;
    const int term  = blockIdx.x - graph * 3;   // 0:(x,y) 1:(x,x) 2:(y,y)
    const float* xb = xg + (size_t)graph * (NPTS * DIM);
    const float* yb = yg + (size_t)graph * (NPTS * DIM);
    const float* Xp = (term == 2) ? yb : xb;
    const float* Yp = (term == 1) ? xb : yb;

    split_store(sxh, sxl, Xp, KLOG, tid);       // row side carries the 1/eps scale
    split_store(syh, syl, Yp, 1.0f, tid);

    // quadratic terms (exact f32) + message init (thread = row)
    float csum;
    {
        const float hx = halfsq16(Xp + tid * DIM);
        const float hy = halfsq16(Yp + tid * DIM);
        csum = hx + hy;
        sB[tid] = fmaf(-KLOG, hy, -10.0f);      // t_j for g = 0
    }
    __syncthreads();

    float fsum = 0.0f, gsum = 0.0f;
    #pragma unroll 1
    for (int it = 0; it < NITERS; ++it) {
        fsum = sink_pass(sxh, sxl, syh, syl, sB, wbase, lane);   // f-update
        gsum = sink_pass(syh, syl, sxh, sxl, sB, wbase, lane);   // g-update
    }
    fsum = sink_pass(sxh, sxl, syh, syl, sB, wbase, lane);       // final f

    // OT = [csum - CLSE*(sum lse_f + sum lse_g)] / NPTS  (lse sums x16 dup)
    float v = fmaf(-CLSE, (fsum + gsum) * (1.0f / 16.0f), csum);
    #pragma unroll
    for (int off = 32; off; off >>= 1) v += __shfl_down(v, off, 64);
    if (lane == 0) sB[wave] = v;
    __syncthreads();
    if (tid == 0) {
        float tot = 0.0f;
        #pragma unroll
        for (int w = 0; w < NWAVES; ++w) tot += sB[w];
        const float wgt = ((term == 0) ? 1.0f : -0.5f)
                          / ((float)GRAPHS * (float)NPTS);
        atomicAdd(out, wgt * tot);
    }
}

extern "C" void kernel_launch(void* const* d_in, const int* in_sizes, int n_in,
                              void* d_out, int out_size, void* d_ws, size_t ws_size,
                              hipStream_t stream)
{
    (void)in_sizes; (void)n_in; (void)d_ws; (void)ws_size; (void)out_size;
    const float* x = (const float*)d_in[0];
    const float* y = (const float*)d_in[1];
    float* out = (float*)d_out;

    constexpr size_t LDSB = 4 * NPTS * DIM * sizeof(__bf16)
                          + NPTS * sizeof(float);          // 132 KiB
    hipFuncSetAttribute((const void*)sinkhorn_kernel,
                        hipFuncAttributeMaxDynamicSharedMemorySize, (int)LDSB);

    hipMemsetAsync(out, 0, sizeof(float), stream);
    hipLaunchKernelGGL(sinkhorn_kernel, dim3(GRAPHS * 3), dim3(THREADS), LDSB,
                       stream, x, y, out);
}